// Round 2
// baseline (942.055 us; speedup 1.0000x reference)
//
#include <hip/hip_runtime.h>

using short8  = __attribute__((ext_vector_type(8))) short;
using floatx4 = __attribute__((ext_vector_type(4))) float;

__device__ inline float b2f(ushort u) {
  union { unsigned u; float f; } x; x.u = ((unsigned)u) << 16; return x.f;
}
__device__ inline ushort f2b(float f) {
  union { float f; unsigned u; } x; x.f = f;
  unsigned r = x.u + 0x7fffu + ((x.u >> 16) & 1u);
  return (ushort)(r >> 16);
}

// async global->LDS, 16B per lane; LDS dest = wave-uniform base + lane*16 (m97/m104)
__device__ __forceinline__ void gl_lds16(const void* g, void* l) {
  __builtin_amdgcn_global_load_lds(
      (const __attribute__((address_space(1))) unsigned*)(unsigned long long)g,
      (__attribute__((address_space(3))) unsigned*)(unsigned)(unsigned long long)l,
      16, 0, 0);
}

// ---------- fp32 -> bf16 bulk convert (n4 = n/4 float4s) ----------
__global__ __launch_bounds__(256) void cvt_f32_bf16(
    const float* __restrict__ in, ushort* __restrict__ out, int n4) {
  const int i = blockIdx.x * 256 + threadIdx.x;
  if (i < n4) {
    const float4 v = ((const float4*)in)[i];
    ushort4 o;
    o.x = f2b(v.x); o.y = f2b(v.y); o.z = f2b(v.z); o.w = f2b(v.w);
    ((ushort4*)out)[i] = o;
  }
}

// ---------- transpose+convert: fp32 W[K][*] (stride ldw) -> bf16 Wt[N][K], 64x64 tiles ----------
// Vectorized both sides: float4 global reads, int4 global writes (G13).
// LDS [k][n] in 4-ushort chunks, chunk ^= (k&15) so the k-strided gather spreads banks.
__global__ __launch_bounds__(256) void transpose_f32_bf16(
    const float* __restrict__ W, int ldw, ushort* __restrict__ Wt, int K) {
  __shared__ ushort tile[64 * 64];
  const int kb = blockIdx.y * 64, nb = blockIdx.x * 64;
  const int t = threadIdx.x;
  {
    const int tn4 = t & 15;          // n-chunk of 4
    const int tk  = t >> 4;          // k row (+16i)
#pragma unroll
    for (int i = 0; i < 4; ++i) {
      const int k = tk + i * 16;
      const float4 v = *(const float4*)&W[(size_t)(kb + k) * ldw + nb + tn4 * 4];
      ushort4 o; o.x = f2b(v.x); o.y = f2b(v.y); o.z = f2b(v.z); o.w = f2b(v.w);
      const int c = tn4 ^ (k & 15);
      *(ushort4*)&tile[k * 64 + c * 4] = o;
    }
  }
  __syncthreads();
  {
    const int kc = t & 7;            // k-chunk of 8
    const int tn = t >> 3;           // n (+32p)
#pragma unroll
    for (int p = 0; p < 2; ++p) {
      const int n = tn + p * 32;
      union { int4 v; ushort u[8]; } o;
#pragma unroll
      for (int j = 0; j < 8; ++j) {
        const int k = kc * 8 + j;
        const int c = (n >> 2) ^ (k & 15);
        o.u[j] = tile[k * 64 + c * 4 + (n & 3)];
      }
      *(int4*)&Wt[(size_t)(nb + n) * K + kb + kc * 8] = o.v;
    }
  }
}

// ---------- one-time V transpose: qkv V-half [2048][4096] -> vT[4096][2048] (bf16) ----------
// int4 global reads and writes; LDS [s][c] in 8-ushort chunks, chunk ^= (s&7)^((s>>3)&7).
__global__ __launch_bounds__(256) void transpose_v_bf16(
    const ushort* __restrict__ qkv, ushort* __restrict__ vT) {
  __shared__ ushort tile[64 * 64];
  const int s0 = blockIdx.y * 64, c0 = blockIdx.x * 64;
  const int t = threadIdx.x;
  {
    const int tc8 = t & 7, ts = t >> 3;     // ts in [0,32)
#pragma unroll
    for (int p = 0; p < 2; ++p) {
      const int s = ts + p * 32;
      int4 x = *(const int4*)(qkv + (size_t)(s0 + s) * 12288 + 8192 + c0 + tc8 * 8);
      const int c8 = tc8 ^ (s & 7) ^ ((s >> 3) & 7);
      *(int4*)&tile[s * 64 + c8 * 8] = x;
    }
  }
  __syncthreads();
  {
    const int sc = t & 7, tc = t >> 3;      // tc in [0,32)
#pragma unroll
    for (int p = 0; p < 2; ++p) {
      const int c = tc + p * 32;
      union { int4 v; ushort u[8]; } o;
#pragma unroll
      for (int j = 0; j < 8; ++j) {
        const int s = sc * 8 + j;
        const int c8 = (c >> 3) ^ (s & 7) ^ ((s >> 3) & 7);
        o.u[j] = tile[s * 64 + c8 * 8 + (c & 7)];
      }
      *(int4*)&vT[(size_t)(c0 + c) * 2048 + s0 + sc * 8] = o.v;
    }
  }
}

// ---------- C[M][N] = A[M][K] @ Bt[N][K]^T + bias(fp32); bf16 in; out bf16 or fp32 ----------
// m97 structure: global_load_lds width-16 staging into unpadded LDS, 2 barriers/K-step.
template <bool F32OUT>
__global__ __launch_bounds__(256) void gemm_bt_bias(
    const ushort* __restrict__ A, const ushort* __restrict__ Bt,
    const float* __restrict__ bias, void* __restrict__ Cout,
    int ldc, int M, int N, int K) {
  __shared__ ushort sA[128 * 64];
  __shared__ ushort sB[128 * 64];
  const int tid = threadIdx.x;
  const int lane = tid & 63, w = tid >> 6;
  const int lm = lane & 15, lq = lane >> 4;
  const int wr = w >> 1, wc = w & 1;
  const int m0 = blockIdx.y * 128, n0 = blockIdx.x * 128;
  floatx4 acc[4][4] = {};

  const int srow = w * 32 + (lane >> 3);     // + j*8
  const int scol = (lane & 7) * 8;
  const ushort* Ag = A + (size_t)(m0 + srow) * K + scol;
  const ushort* Bg = Bt + (size_t)(n0 + srow) * K + scol;

  for (int k0 = 0; k0 < K; k0 += 64) {
    __syncthreads();
#pragma unroll
    for (int j = 0; j < 4; ++j) {
      gl_lds16(Ag + (size_t)j * 8 * K + k0, &sA[(w * 32 + j * 8) * 64]);
      gl_lds16(Bg + (size_t)j * 8 * K + k0, &sB[(w * 32 + j * 8) * 64]);
    }
    __syncthreads();
#pragma unroll
    for (int ks = 0; ks < 2; ++ks) {
      short8 af[4], bf[4];
#pragma unroll
      for (int i = 0; i < 4; ++i)
        af[i] = *(const short8*)&sA[(wr * 64 + i * 16 + lm) * 64 + ks * 32 + lq * 8];
#pragma unroll
      for (int j = 0; j < 4; ++j)
        bf[j] = *(const short8*)&sB[(wc * 64 + j * 16 + lm) * 64 + ks * 32 + lq * 8];
#pragma unroll
      for (int i = 0; i < 4; ++i)
#pragma unroll
        for (int j = 0; j < 4; ++j)
          acc[i][j] = __builtin_amdgcn_mfma_f32_16x16x32_bf16(af[i], bf[j], acc[i][j], 0, 0, 0);
    }
  }
#pragma unroll
  for (int i = 0; i < 4; ++i) {
#pragma unroll
    for (int j = 0; j < 4; ++j) {
      const int row = m0 + wr * 64 + i * 16 + lq * 4;
      const int col = n0 + wc * 64 + j * 16 + lm;
      const float bs = bias[col];
      if (F32OUT) {
        float* C = (float*)Cout;
#pragma unroll
        for (int r = 0; r < 4; ++r)
          C[(size_t)(row + r) * ldc + col] = acc[i][j][r] + bs;
      } else {
        ushort* C = (ushort*)Cout;
#pragma unroll
        for (int r = 0; r < 4; ++r)
          C[(size_t)(row + r) * ldc + col] = f2b(acc[i][j][r] + bs);
      }
    }
  }
}

// ---------- RoPE in-place on q,k halves of qkv bf16 [2048][12288], int4 vectorized ----------
__global__ __launch_bounds__(256) void rope_kernel(ushort* __restrict__ qkv) {
  const int s = blockIdx.x;
  const float pos = (float)s;
  const int t = threadIdx.x;
  const int h = t >> 3, d8 = (t & 7) * 8;
  const size_t base = (size_t)s * 12288 + h * 128 + d8;
  union U { int4 v; ushort u[8]; };
  U q1, q2, k1, k2;
  q1.v = *(const int4*)(qkv + base);
  q2.v = *(const int4*)(qkv + base + 64);
  k1.v = *(const int4*)(qkv + base + 4096);
  k2.v = *(const int4*)(qkv + base + 4160);
  float sn[8], cs[8];
#pragma unroll
  for (int j = 0; j < 8; ++j) {
    const float inv_freq = exp2f(-(float)(d8 + j) * 0.20762050593045952f); // 10000^(-d/64)
    sincosf(pos * inv_freq, &sn[j], &cs[j]);
  }
  U o1, o2;
#pragma unroll
  for (int j = 0; j < 8; ++j) {
    const float x1 = b2f(q1.u[j]), x2 = b2f(q2.u[j]);
    o1.u[j] = f2b(x1 * cs[j] - x2 * sn[j]);
    o2.u[j] = f2b(x2 * cs[j] + x1 * sn[j]);
  }
  *(int4*)(qkv + base)      = o1.v;
  *(int4*)(qkv + base + 64) = o2.v;
#pragma unroll
  for (int j = 0; j < 8; ++j) {
    const float x1 = b2f(k1.u[j]), x2 = b2f(k2.u[j]);
    o1.u[j] = f2b(x1 * cs[j] - x2 * sn[j]);
    o2.u[j] = f2b(x2 * cs[j] + x1 * sn[j]);
  }
  *(int4*)(qkv + base + 4096) = o1.v;
  *(int4*)(qkv + base + 4160) = o2.v;
}

// ---------- causal flash attention: one 64-row q-tile/block, 1024 blocks, longest-first ----------
// T2: all LDS tiles DMA-staged (global_load_lds w16) with 16B-chunk XOR swizzle
// (linear dest + inverse-swizzled SOURCE + swizzled READ — rule #21).
__global__ __launch_bounds__(256) void flash_kernel(
    const ushort* __restrict__ qkv, const ushort* __restrict__ vT,
    ushort* __restrict__ attn) {
  constexpr int QKV = 12288;
  __shared__ ushort smem[20480];          // 40960 B -> 4 blocks/CU
  ushort* sK  = smem;                     // 64 x 128 (also sQ; aliased)
  ushort* sVt = smem + 8192;              // 128 (d) x 64 (kv)
  ushort* sP  = smem + 16384;             // 64 (q) x 64 (kv)

  const int h   = blockIdx.y;
  const int tid = threadIdx.x;
  const int lane = tid & 63, w = tid >> 6;
  const int lm = lane & 15, lq = lane >> 4;
  const int c16 = lane & 15, l4 = lane >> 4;   // K/Q staging: 16 chunks/row, 4 rows/call
  const int c8  = lane & 7,  l3 = lane >> 3;   // V staging: 8 chunks/row, 8 rows/call
  const float sc = 0.08838834764831845f * 1.4426950408889634f; // 1/sqrt(128) * log2(e)

  const int qt = 31 - blockIdx.x;         // longest blocks dispatch first
  const int q0 = qt * 64;

  // stage 64x128 Q tile, chunk-swizzled source -> linear LDS
#pragma unroll
  for (int j = 0; j < 4; ++j) {
    const int row = w * 16 + j * 4 + l4;
    const int sw = c16 ^ (row & 7);
    gl_lds16(qkv + (size_t)(q0 + row) * QKV + h * 128 + sw * 8,
             &sK[(w * 16 + j * 4) * 128]);
  }
  __syncthreads();   // DMA drained
  short8 aq[4];
#pragma unroll
  for (int kk = 0; kk < 4; ++kk)
    aq[kk] = *(const short8*)&sK[(w * 16 + lm) * 128 + (((kk * 4 + lq) ^ (lm & 7)) * 8)];

  floatx4 acco[8] = {};
  float mrun[4], lrun[4];
#pragma unroll
  for (int r = 0; r < 4; ++r) { mrun[r] = -1e30f; lrun[r] = 0.f; }

  const int nkv = qt + 1;
  for (int it = 0; it < nkv; ++it) {
    const int kv0 = it * 64;
    __syncthreads();   // all waves done with prev tile's sK/sVt (and aq reads)
    // K tile [64 kv][128 d]
#pragma unroll
    for (int j = 0; j < 4; ++j) {
      const int row = w * 16 + j * 4 + l4;
      const int sw = c16 ^ (row & 7);
      gl_lds16(qkv + (size_t)(kv0 + row) * QKV + 4096 + h * 128 + sw * 8,
               &sK[(w * 16 + j * 4) * 128]);
    }
    // V^T tile [128 d][64 kv] from global vT (no in-loop transpose)
#pragma unroll
    for (int j = 0; j < 4; ++j) {
      const int vrow = w * 32 + j * 8 + l3;
      const int sw = c8 ^ (vrow & 7);
      gl_lds16(vT + (size_t)(h * 128 + vrow) * 2048 + kv0 + sw * 8,
               &sVt[(w * 32 + j * 8) * 64]);
    }
    __syncthreads();   // DMA drained

    // S = Q K^T  (this wave: q rows w*16..w*16+15)
    floatx4 accs[4] = {};
#pragma unroll
    for (int kk = 0; kk < 4; ++kk) {
      short8 bk[4];
#pragma unroll
      for (int nt = 0; nt < 4; ++nt)
        bk[nt] = *(const short8*)&sK[(nt * 16 + lm) * 128 + (((kk * 4 + lq) ^ (lm & 7)) * 8)];
#pragma unroll
      for (int nt = 0; nt < 4; ++nt)
        accs[nt] = __builtin_amdgcn_mfma_f32_16x16x32_bf16(aq[kk], bk[nt], accs[nt], 0, 0, 0);
    }

    // scale + causal mask + tile row-max
    const bool domask = (it == nkv - 1);
    float tmax[4];
#pragma unroll
    for (int r = 0; r < 4; ++r) tmax[r] = -1e30f;
#pragma unroll
    for (int nt = 0; nt < 4; ++nt)
#pragma unroll
      for (int r = 0; r < 4; ++r) {
        float v = accs[nt][r] * sc;
        if (domask) {
          const int qrow = q0 + w * 16 + lq * 4 + r;
          const int kcol = kv0 + nt * 16 + lm;
          if (kcol > qrow) v = -1e30f;
        }
        accs[nt][r] = v;
        tmax[r] = fmaxf(tmax[r], v);
      }
    // online softmax update
#pragma unroll
    for (int r = 0; r < 4; ++r) {
      float t = tmax[r];
#pragma unroll
      for (int off = 1; off < 16; off <<= 1) t = fmaxf(t, __shfl_xor(t, off, 64));
      const float mnew = fmaxf(mrun[r], t);
      const float alpha = exp2f(mrun[r] - mnew);
      mrun[r] = mnew;
      lrun[r] *= alpha;
#pragma unroll
      for (int nt = 0; nt < 8; ++nt) acco[nt][r] *= alpha;
    }
    // P = exp2(s - m) -> sP (wave-private rows, chunk-swizzled)
    float rsum[4] = {};
#pragma unroll
    for (int nt = 0; nt < 4; ++nt)
#pragma unroll
      for (int r = 0; r < 4; ++r) {
        const float p = exp2f(accs[nt][r] - mrun[r]);
        rsum[r] += p;
        sP[(w * 16 + lq * 4 + r) * 64 +
           (((2 * nt + (lm >> 3)) ^ ((lq * 4 + r) & 7)) * 8) + (lm & 7)] = f2b(p);
      }
#pragma unroll
    for (int r = 0; r < 4; ++r) {
      float t = rsum[r];
#pragma unroll
      for (int off = 1; off < 16; off <<= 1) t += __shfl_xor(t, off, 64);
      lrun[r] += t;
    }

    // O += P @ V
#pragma unroll
    for (int ks = 0; ks < 2; ++ks) {
      const short8 ap = *(const short8*)&sP[(w * 16 + lm) * 64 + (((ks * 4 + lq) ^ (lm & 7)) * 8)];
#pragma unroll
      for (int nt = 0; nt < 8; ++nt) {
        const short8 bv = *(const short8*)&sVt[(nt * 16 + lm) * 64 + (((ks * 4 + lq) ^ (lm & 7)) * 8)];
        acco[nt] = __builtin_amdgcn_mfma_f32_16x16x32_bf16(ap, bv, acco[nt], 0, 0, 0);
      }
    }
  }

  // epilogue: O / l -> attn
#pragma unroll
  for (int r = 0; r < 4; ++r) {
    const float inv = 1.0f / lrun[r];
    const int row = q0 + w * 16 + lq * 4 + r;
#pragma unroll
    for (int nt = 0; nt < 8; ++nt) {
      const int col = h * 128 + nt * 16 + lm;
      attn[(size_t)row * 4096 + col] = f2b(acco[nt][r] * inv);
    }
  }
}

extern "C" void kernel_launch(void* const* d_in, const int* in_sizes, int n_in,
                              void* d_out, int out_size, void* d_ws, size_t ws_size,
                              hipStream_t stream) {
  // inputs (fp32): 0=positions(int, unused), 1=hidden [2048][4096],
  // 2=Wqkv [4096][12288], 3=bqkv [12288], 4=Wo [4096][4096], 5=bo [4096].
  // Output fp32 [2048][4096].
  const float* hidden = (const float*)d_in[1];
  const float* Wqkv   = (const float*)d_in[2];
  const float* bqkv   = (const float*)d_in[3];
  const float* Wo     = (const float*)d_in[4];
  const float* bo     = (const float*)d_in[5];

  // ws layout (bf16 elements), peak 112 MiB:
  ushort* ws   = (ushort*)d_ws;
  ushort* Wt   = ws;                          // 16,777,216  (32 MiB; also hosts vT between QKV-GEMMs and Wo-transpose)
  ushort* hb   = ws + (size_t)16777216;       //  8,388,608  (16 MiB) hidden bf16
  ushort* qkv  = ws + (size_t)25165824;       // 25,165,824  (48 MiB)
  ushort* attn = ws + (size_t)50331648;       //  8,388,608  (16 MiB)

  cvt_f32_bf16<<<8192, 256, 0, stream>>>(hidden, hb, 2097152);

  for (int c = 0; c < 3; ++c) {
    transpose_f32_bf16<<<dim3(64, 64), 256, 0, stream>>>(Wqkv + c * 4096, 12288, Wt, 4096);
    gemm_bt_bias<false><<<dim3(32, 16), 256, 0, stream>>>(
        hb, Wt, bqkv + c * 4096, (void*)(qkv + c * 4096), 12288, 2048, 4096, 4096);
  }

  rope_kernel<<<2048, 256, 0, stream>>>(qkv);
  // vT[4096][2048] into the (currently idle) Wt region
  transpose_v_bf16<<<dim3(64, 32), 256, 0, stream>>>(qkv, Wt);
  flash_kernel<<<dim3(32, 32), 256, 0, stream>>>(qkv, Wt, attn);

  transpose_f32_bf16<<<dim3(64, 64), 256, 0, stream>>>(Wo, 4096, Wt, 4096);
  gemm_bt_bias<true><<<dim3(32, 16), 256, 0, stream>>>(
      attn, Wt, bo, d_out, 4096, 2048, 4096, 4096);
}

// Round 3
// 899.981 us; speedup vs baseline: 1.0467x; 1.0467x over previous
//
#include <hip/hip_runtime.h>

using short8  = __attribute__((ext_vector_type(8))) short;
using floatx4 = __attribute__((ext_vector_type(4))) float;

__device__ inline float b2f(ushort u) {
  union { unsigned u; float f; } x; x.u = ((unsigned)u) << 16; return x.f;
}
__device__ inline ushort f2b(float f) {
  union { float f; unsigned u; } x; x.f = f;
  unsigned r = x.u + 0x7fffu + ((x.u >> 16) & 1u);
  return (ushort)(r >> 16);
}

// async global->LDS, 16B per lane; LDS dest = wave-uniform base + lane*16 (m97/m104)
__device__ __forceinline__ void gl_lds16(const void* g, void* l) {
  __builtin_amdgcn_global_load_lds(
      (const __attribute__((address_space(1))) unsigned*)(unsigned long long)g,
      (__attribute__((address_space(3))) unsigned*)(unsigned)(unsigned long long)l,
      16, 0, 0);
}

// ---------- fp32 -> bf16 bulk convert (n4 = n/4 float4s) ----------
__global__ __launch_bounds__(256) void cvt_f32_bf16(
    const float* __restrict__ in, ushort* __restrict__ out, int n4) {
  const int i = blockIdx.x * 256 + threadIdx.x;
  if (i < n4) {
    const float4 v = ((const float4*)in)[i];
    ushort4 o;
    o.x = f2b(v.x); o.y = f2b(v.y); o.z = f2b(v.z); o.w = f2b(v.w);
    ((ushort4*)out)[i] = o;
  }
}

// ---------- transpose+convert: fp32 W[K][*] (stride ldw) -> bf16 Wt[N][K], 64x64 tiles ----------
// Vectorized both sides: float4 global reads, int4 global writes (G13).
__global__ __launch_bounds__(256) void transpose_f32_bf16(
    const float* __restrict__ W, int ldw, ushort* __restrict__ Wt, int K) {
  __shared__ ushort tile[64 * 64];
  const int kb = blockIdx.y * 64, nb = blockIdx.x * 64;
  const int t = threadIdx.x;
  {
    const int tn4 = t & 15;          // n-chunk of 4
    const int tk  = t >> 4;          // k row (+16i)
#pragma unroll
    for (int i = 0; i < 4; ++i) {
      const int k = tk + i * 16;
      const float4 v = *(const float4*)&W[(size_t)(kb + k) * ldw + nb + tn4 * 4];
      ushort4 o; o.x = f2b(v.x); o.y = f2b(v.y); o.z = f2b(v.z); o.w = f2b(v.w);
      const int c = tn4 ^ (k & 15);
      *(ushort4*)&tile[k * 64 + c * 4] = o;
    }
  }
  __syncthreads();
  {
    const int kc = t & 7;            // k-chunk of 8
    const int tn = t >> 3;           // n (+32p)
#pragma unroll
    for (int p = 0; p < 2; ++p) {
      const int n = tn + p * 32;
      union { int4 v; ushort u[8]; } o;
#pragma unroll
      for (int j = 0; j < 8; ++j) {
        const int k = kc * 8 + j;
        const int c = (n >> 2) ^ (k & 15);
        o.u[j] = tile[k * 64 + c * 4 + (n & 3)];
      }
      *(int4*)&Wt[(size_t)(nb + n) * K + kb + kc * 8] = o.v;
    }
  }
}

// ---------- one-time V transpose: qkv V-half [2048][4096] -> vT[4096][2048] (bf16) ----------
__global__ __launch_bounds__(256) void transpose_v_bf16(
    const ushort* __restrict__ qkv, ushort* __restrict__ vT) {
  __shared__ ushort tile[64 * 64];
  const int s0 = blockIdx.y * 64, c0 = blockIdx.x * 64;
  const int t = threadIdx.x;
  {
    const int tc8 = t & 7, ts = t >> 3;     // ts in [0,32)
#pragma unroll
    for (int p = 0; p < 2; ++p) {
      const int s = ts + p * 32;
      int4 x = *(const int4*)(qkv + (size_t)(s0 + s) * 12288 + 8192 + c0 + tc8 * 8);
      const int c8 = tc8 ^ (s & 7) ^ ((s >> 3) & 7);
      *(int4*)&tile[s * 64 + c8 * 8] = x;
    }
  }
  __syncthreads();
  {
    const int sc = t & 7, tc = t >> 3;      // tc in [0,32)
#pragma unroll
    for (int p = 0; p < 2; ++p) {
      const int c = tc + p * 32;
      union { int4 v; ushort u[8]; } o;
#pragma unroll
      for (int j = 0; j < 8; ++j) {
        const int s = sc * 8 + j;
        const int c8 = (c >> 3) ^ (s & 7) ^ ((s >> 3) & 7);
        o.u[j] = tile[s * 64 + c8 * 8 + (c & 7)];
      }
      *(int4*)&vT[(size_t)(c0 + c) * 2048 + s0 + sc * 8] = o.v;
    }
  }
}

// ---------- C[M][N] = A[M][K] @ Bt[N][K]^T + bias(fp32); bf16 in; out bf16 or fp32 ----------
// m97 structure: global_load_lds width-16 staging into unpadded LDS, 2 barriers/K-step.
template <bool F32OUT>
__global__ __launch_bounds__(256) void gemm_bt_bias(
    const ushort* __restrict__ A, const ushort* __restrict__ Bt,
    const float* __restrict__ bias, void* __restrict__ Cout,
    int ldc, int M, int N, int K) {
  __shared__ ushort sA[128 * 64];
  __shared__ ushort sB[128 * 64];
  const int tid = threadIdx.x;
  const int lane = tid & 63, w = tid >> 6;
  const int lm = lane & 15, lq = lane >> 4;
  const int wr = w >> 1, wc = w & 1;
  const int m0 = blockIdx.y * 128, n0 = blockIdx.x * 128;
  floatx4 acc[4][4] = {};

  const int srow = w * 32 + (lane >> 3);     // + j*8
  const int scol = (lane & 7) * 8;
  const ushort* Ag = A + (size_t)(m0 + srow) * K + scol;
  const ushort* Bg = Bt + (size_t)(n0 + srow) * K + scol;

  for (int k0 = 0; k0 < K; k0 += 64) {
    __syncthreads();
#pragma unroll
    for (int j = 0; j < 4; ++j) {
      gl_lds16(Ag + (size_t)j * 8 * K + k0, &sA[(w * 32 + j * 8) * 64]);
      gl_lds16(Bg + (size_t)j * 8 * K + k0, &sB[(w * 32 + j * 8) * 64]);
    }
    __syncthreads();
#pragma unroll
    for (int ks = 0; ks < 2; ++ks) {
      short8 af[4], bf[4];
#pragma unroll
      for (int i = 0; i < 4; ++i)
        af[i] = *(const short8*)&sA[(wr * 64 + i * 16 + lm) * 64 + ks * 32 + lq * 8];
#pragma unroll
      for (int j = 0; j < 4; ++j)
        bf[j] = *(const short8*)&sB[(wc * 64 + j * 16 + lm) * 64 + ks * 32 + lq * 8];
#pragma unroll
      for (int i = 0; i < 4; ++i)
#pragma unroll
        for (int j = 0; j < 4; ++j)
          acc[i][j] = __builtin_amdgcn_mfma_f32_16x16x32_bf16(af[i], bf[j], acc[i][j], 0, 0, 0);
    }
  }
#pragma unroll
  for (int i = 0; i < 4; ++i) {
#pragma unroll
    for (int j = 0; j < 4; ++j) {
      const int row = m0 + wr * 64 + i * 16 + lq * 4;
      const int col = n0 + wc * 64 + j * 16 + lm;
      const float bs = bias[col];
      if (F32OUT) {
        float* C = (float*)Cout;
#pragma unroll
        for (int r = 0; r < 4; ++r)
          C[(size_t)(row + r) * ldc + col] = acc[i][j][r] + bs;
      } else {
        ushort* C = (ushort*)Cout;
#pragma unroll
        for (int r = 0; r < 4; ++r)
          C[(size_t)(row + r) * ldc + col] = f2b(acc[i][j][r] + bs);
      }
    }
  }
}

// ---------- RoPE in-place on q,k halves of qkv bf16 [2048][12288], int4 vectorized ----------
__global__ __launch_bounds__(256) void rope_kernel(ushort* __restrict__ qkv) {
  const int s = blockIdx.x;
  const float pos = (float)s;
  const int t = threadIdx.x;
  const int h = t >> 3, d8 = (t & 7) * 8;
  const size_t base = (size_t)s * 12288 + h * 128 + d8;
  union U { int4 v; ushort u[8]; };
  U q1, q2, k1, k2;
  q1.v = *(const int4*)(qkv + base);
  q2.v = *(const int4*)(qkv + base + 64);
  k1.v = *(const int4*)(qkv + base + 4096);
  k2.v = *(const int4*)(qkv + base + 4160);
  float sn[8], cs[8];
#pragma unroll
  for (int j = 0; j < 8; ++j) {
    const float inv_freq = exp2f(-(float)(d8 + j) * 0.20762050593045952f); // 10000^(-d/64)
    sincosf(pos * inv_freq, &sn[j], &cs[j]);
  }
  U o1, o2;
#pragma unroll
  for (int j = 0; j < 8; ++j) {
    const float x1 = b2f(q1.u[j]), x2 = b2f(q2.u[j]);
    o1.u[j] = f2b(x1 * cs[j] - x2 * sn[j]);
    o2.u[j] = f2b(x2 * cs[j] + x1 * sn[j]);
  }
  *(int4*)(qkv + base)      = o1.v;
  *(int4*)(qkv + base + 64) = o2.v;
#pragma unroll
  for (int j = 0; j < 8; ++j) {
    const float x1 = b2f(k1.u[j]), x2 = b2f(k2.u[j]);
    o1.u[j] = f2b(x1 * cs[j] - x2 * sn[j]);
    o2.u[j] = f2b(x2 * cs[j] + x1 * sn[j]);
  }
  *(int4*)(qkv + base + 4096) = o1.v;
  *(int4*)(qkv + base + 4160) = o2.v;
}

// ---------- causal flash attention: paired q-tiles (balanced 33 kv-iters/block) ----------
// 2-phase pipeline: double-buffered K/V tiles, STAGE(t+1) issued before compute(t),
// one barrier per iter (T3-minimum). sP is wave-private (no barrier needed).
// Exact defer-rescale: skip alpha pass when no row's tile-max exceeds running max.
__global__ __launch_bounds__(256) void flash_kernel(
    const ushort* __restrict__ qkv, const ushort* __restrict__ vT,
    ushort* __restrict__ attn) {
  constexpr int QKV = 12288;
  __shared__ ushort smem[36864];          // 72 KB -> 2 blocks/CU (grid-matched)
  // buf c: sK = smem + c*8192 (64x128), sV = smem + 16384 + c*8192 (128x64)
  ushort* sP = smem + 32768;              // 64 (q) x 64 (kv), wave-private rows

  const int h   = blockIdx.y;
  const int tid = threadIdx.x;
  const int lane = tid & 63, w = tid >> 6;
  const int lm = lane & 15, lq = lane >> 4;
  const int c16 = lane & 15, l4 = lane >> 4;   // K/Q staging: 16 chunks/row, 4 rows/call
  const int c8  = lane & 7,  l3 = lane >> 3;   // V staging: 8 chunks/row, 8 rows/call
  const float sc = 0.08838834764831845f * 1.4426950408889634f; // 1/sqrt(128) * log2(e)

  for (int qsel = 0; qsel < 2; ++qsel) {
    // pair long tile (31-bx) with short tile (bx): every block does 33 kv-iters
    const int qt = qsel ? (int)blockIdx.x : 31 - (int)blockIdx.x;
    const int q0 = qt * 64;
    const int nkv = qt + 1;

    __syncthreads();   // prior half fully done with LDS
    // stage Q into buf1-K region; stage tile 0 into buf0
#pragma unroll
    for (int j = 0; j < 4; ++j) {
      const int row = w * 16 + j * 4 + l4;
      const int sw = c16 ^ (row & 7);
      gl_lds16(qkv + (size_t)(q0 + row) * QKV + h * 128 + sw * 8,
               &smem[8192 + (w * 16 + j * 4) * 128]);
    }
#pragma unroll
    for (int j = 0; j < 4; ++j) {
      const int row = w * 16 + j * 4 + l4;
      const int sw = c16 ^ (row & 7);
      gl_lds16(qkv + (size_t)row * QKV + 4096 + h * 128 + sw * 8,
               &smem[(w * 16 + j * 4) * 128]);
    }
#pragma unroll
    for (int j = 0; j < 4; ++j) {
      const int vrow = w * 32 + j * 8 + l3;
      const int sw = c8 ^ (vrow & 7);
      gl_lds16(vT + (size_t)(h * 128 + vrow) * 2048 + sw * 8,
               &smem[16384 + (w * 32 + j * 8) * 64]);
    }
    __syncthreads();   // DMA drained (Q + tile 0)
    short8 aq[4];
#pragma unroll
    for (int kk = 0; kk < 4; ++kk)
      aq[kk] = *(const short8*)&smem[8192 + (w * 16 + lm) * 128 + (((kk * 4 + lq) ^ (lm & 7)) * 8)];
    __syncthreads();   // all aq reads done before iter 0 stages buf1

    floatx4 acco[8] = {};
    float mrun[4], lrun[4];
#pragma unroll
    for (int r = 0; r < 4; ++r) { mrun[r] = -1e30f; lrun[r] = 0.f; }

    for (int it = 0; it < nkv; ++it) {
      const int cur = it & 1;
      ushort* dK = smem + cur * 8192;
      ushort* dV = smem + 16384 + cur * 8192;

      // prefetch tile it+1 into the other buffer (its readers finished at end of it-1)
      if (it + 1 < nkv) {
        const int kv1 = (it + 1) * 64;
        ushort* pK = smem + (cur ^ 1) * 8192;
        ushort* pV = smem + 16384 + (cur ^ 1) * 8192;
#pragma unroll
        for (int j = 0; j < 4; ++j) {
          const int row = w * 16 + j * 4 + l4;
          const int sw = c16 ^ (row & 7);
          gl_lds16(qkv + (size_t)(kv1 + row) * QKV + 4096 + h * 128 + sw * 8,
                   &pK[(w * 16 + j * 4) * 128]);
        }
#pragma unroll
        for (int j = 0; j < 4; ++j) {
          const int vrow = w * 32 + j * 8 + l3;
          const int sw = c8 ^ (vrow & 7);
          gl_lds16(vT + (size_t)(h * 128 + vrow) * 2048 + kv1 + sw * 8,
                   &pV[(w * 32 + j * 8) * 64]);
        }
      }

      const int kv0 = it * 64;
      // S = Q K^T  (this wave: q rows w*16..w*16+15)
      floatx4 accs[4] = {};
#pragma unroll
      for (int kk = 0; kk < 4; ++kk) {
        short8 bk[4];
#pragma unroll
        for (int nt = 0; nt < 4; ++nt)
          bk[nt] = *(const short8*)&dK[(nt * 16 + lm) * 128 + (((kk * 4 + lq) ^ (lm & 7)) * 8)];
#pragma unroll
        for (int nt = 0; nt < 4; ++nt)
          accs[nt] = __builtin_amdgcn_mfma_f32_16x16x32_bf16(aq[kk], bk[nt], accs[nt], 0, 0, 0);
      }

      // scale + causal mask + tile row-max
      const bool domask = (it == nkv - 1);
      float tmax[4];
#pragma unroll
      for (int r = 0; r < 4; ++r) tmax[r] = -1e30f;
#pragma unroll
      for (int nt = 0; nt < 4; ++nt)
#pragma unroll
        for (int r = 0; r < 4; ++r) {
          float v = accs[nt][r] * sc;
          if (domask) {
            const int qrow = q0 + w * 16 + lq * 4 + r;
            const int kcol = kv0 + nt * 16 + lm;
            if (kcol > qrow) v = -1e30f;
          }
          accs[nt][r] = v;
          tmax[r] = fmaxf(tmax[r], v);
        }
      // row-max reduce (16-lane groups)
      float tr[4];
#pragma unroll
      for (int r = 0; r < 4; ++r) {
        float t = tmax[r];
#pragma unroll
        for (int off = 1; off < 16; off <<= 1) t = fmaxf(t, __shfl_xor(t, off, 64));
        tr[r] = t;
      }
      // exact defer-rescale: if no row grew its max, alpha == 1 for every row -> skip
      unsigned long long need = 0;
#pragma unroll
      for (int r = 0; r < 4; ++r) need |= __ballot(tr[r] > mrun[r]);
      if (need) {
#pragma unroll
        for (int r = 0; r < 4; ++r) {
          const float mnew = fmaxf(mrun[r], tr[r]);
          const float alpha = exp2f(mrun[r] - mnew);
          mrun[r] = mnew;
          lrun[r] *= alpha;
#pragma unroll
          for (int nt = 0; nt < 8; ++nt) acco[nt][r] *= alpha;
        }
      }
      // P = exp2(s - m) -> sP (wave-private rows, chunk-swizzled)
      float rsum[4] = {};
#pragma unroll
      for (int nt = 0; nt < 4; ++nt)
#pragma unroll
        for (int r = 0; r < 4; ++r) {
          const float p = exp2f(accs[nt][r] - mrun[r]);
          rsum[r] += p;
          sP[(w * 16 + lq * 4 + r) * 64 +
             (((2 * nt + (lm >> 3)) ^ ((lq * 4 + r) & 7)) * 8) + (lm & 7)] = f2b(p);
        }
#pragma unroll
      for (int r = 0; r < 4; ++r) {
        float t = rsum[r];
#pragma unroll
        for (int off = 1; off < 16; off <<= 1) t += __shfl_xor(t, off, 64);
        lrun[r] += t;
      }

      // O += P @ V
#pragma unroll
      for (int ks = 0; ks < 2; ++ks) {
        const short8 ap = *(const short8*)&sP[(w * 16 + lm) * 64 + (((ks * 4 + lq) ^ (lm & 7)) * 8)];
#pragma unroll
        for (int nt = 0; nt < 8; ++nt) {
          const short8 bv = *(const short8*)&dV[(nt * 16 + lm) * 64 + (((ks * 4 + lq) ^ (lm & 7)) * 8)];
          acco[nt] = __builtin_amdgcn_mfma_f32_16x16x32_bf16(ap, bv, acco[nt], 0, 0, 0);
        }
      }
      __syncthreads();  // next tile's DMA drained (vmcnt0+lgkm0 implied); readers of cur done
    }

    // epilogue: O / l -> attn
#pragma unroll
    for (int r = 0; r < 4; ++r) {
      const float inv = 1.0f / lrun[r];
      const int row = q0 + w * 16 + lq * 4 + r;
#pragma unroll
      for (int nt = 0; nt < 8; ++nt) {
        const int col = h * 128 + nt * 16 + lm;
        attn[(size_t)row * 4096 + col] = f2b(acco[nt][r] * inv);
      }
    }
  }
}

extern "C" void kernel_launch(void* const* d_in, const int* in_sizes, int n_in,
                              void* d_out, int out_size, void* d_ws, size_t ws_size,
                              hipStream_t stream) {
  // inputs (fp32): 0=positions(int, unused), 1=hidden [2048][4096],
  // 2=Wqkv [4096][12288], 3=bqkv [12288], 4=Wo [4096][4096], 5=bo [4096].
  // Output fp32 [2048][4096].
  const float* hidden = (const float*)d_in[1];
  const float* Wqkv   = (const float*)d_in[2];
  const float* bqkv   = (const float*)d_in[3];
  const float* Wo     = (const float*)d_in[4];
  const float* bo     = (const float*)d_in[5];

  // ws layout (bf16 elements):
  //   hb   @ 0          8,388,608  (16 MiB)
  //   qkv  @ 8,388,608 25,165,824  (48 MiB)
  //   attn @33,554,432  8,388,608  (16 MiB)
  //   Wt   @41,943,040  fused: 50,331,648 el (96 MiB, full Wqkv^T) -> peak 176 MiB
  //                     fallback: 16,777,216 el (32 MiB)          -> peak 112 MiB
  ushort* ws   = (ushort*)d_ws;
  ushort* hb   = ws;
  ushort* qkv  = ws + (size_t)8388608;
  ushort* attn = ws + (size_t)33554432;
  ushort* Wt   = ws + (size_t)41943040;

  cvt_f32_bf16<<<8192, 256, 0, stream>>>(hidden, hb, 2097152);

  const bool fused = ws_size >= (size_t)184549376;  // 176 MiB
  if (fused) {
    // one transpose + one M=2048,N=12288,K=4096 GEMM (1536 blocks, ~3/CU resident)
    transpose_f32_bf16<<<dim3(192, 64), 256, 0, stream>>>(Wqkv, 12288, Wt, 4096);
    gemm_bt_bias<false><<<dim3(96, 16), 256, 0, stream>>>(
        hb, Wt, bqkv, (void*)qkv, 12288, 2048, 12288, 4096);
  } else {
    for (int c = 0; c < 3; ++c) {
      transpose_f32_bf16<<<dim3(64, 64), 256, 0, stream>>>(Wqkv + c * 4096, 12288, Wt, 4096);
      gemm_bt_bias<false><<<dim3(32, 16), 256, 0, stream>>>(
          hb, Wt, bqkv + c * 4096, (void*)(qkv + c * 4096), 12288, 2048, 4096, 4096);
    }
  }

  rope_kernel<<<2048, 256, 0, stream>>>(qkv);
  // vT[4096][2048] into the (now idle) Wt region
  transpose_v_bf16<<<dim3(64, 32), 256, 0, stream>>>(qkv, Wt);
  flash_kernel<<<dim3(16, 32), 256, 0, stream>>>(qkv, Wt, attn);

  transpose_f32_bf16<<<dim3(64, 64), 256, 0, stream>>>(Wo, 4096, Wt, 4096);
  gemm_bt_bias<true><<<dim3(32, 16), 256, 0, stream>>>(
      attn, Wt, bo, d_out, 4096, 2048, 4096, 4096);
}

// Round 4
// 764.834 us; speedup vs baseline: 1.2317x; 1.1767x over previous
//
#include <hip/hip_runtime.h>

using short8  = __attribute__((ext_vector_type(8))) short;
using floatx4 = __attribute__((ext_vector_type(4))) float;

__device__ inline float b2f(ushort u) {
  union { unsigned u; float f; } x; x.u = ((unsigned)u) << 16; return x.f;
}
__device__ inline ushort f2b(float f) {
  union { float f; unsigned u; } x; x.f = f;
  unsigned r = x.u + 0x7fffu + ((x.u >> 16) & 1u);
  return (ushort)(r >> 16);
}

// async global->LDS, 16B per lane; LDS dest = wave-uniform base + lane*16 (m97/m104)
__device__ __forceinline__ void gl_lds16(const void* g, void* l) {
  __builtin_amdgcn_global_load_lds(
      (const __attribute__((address_space(1))) unsigned*)(unsigned long long)g,
      (__attribute__((address_space(3))) unsigned*)(unsigned)(unsigned long long)l,
      16, 0, 0);
}

// ---------- fp32 -> bf16 bulk convert (n4 = n/4 float4s) ----------
__global__ __launch_bounds__(256) void cvt_f32_bf16(
    const float* __restrict__ in, ushort* __restrict__ out, int n4) {
  const int i = blockIdx.x * 256 + threadIdx.x;
  if (i < n4) {
    const float4 v = ((const float4*)in)[i];
    ushort4 o;
    o.x = f2b(v.x); o.y = f2b(v.y); o.z = f2b(v.z); o.w = f2b(v.w);
    ((ushort4*)out)[i] = o;
  }
}

// ---------- transpose+convert: fp32 W[K][*] (stride ldw) -> bf16 Wt[N][K], 64x64 tiles ----------
// Vectorized both sides: float4 global reads, int4 global writes (G13).
__global__ __launch_bounds__(256) void transpose_f32_bf16(
    const float* __restrict__ W, int ldw, ushort* __restrict__ Wt, int K) {
  __shared__ ushort tile[64 * 64];
  const int kb = blockIdx.y * 64, nb = blockIdx.x * 64;
  const int t = threadIdx.x;
  {
    const int tn4 = t & 15;          // n-chunk of 4
    const int tk  = t >> 4;          // k row (+16i)
#pragma unroll
    for (int i = 0; i < 4; ++i) {
      const int k = tk + i * 16;
      const float4 v = *(const float4*)&W[(size_t)(kb + k) * ldw + nb + tn4 * 4];
      ushort4 o; o.x = f2b(v.x); o.y = f2b(v.y); o.z = f2b(v.z); o.w = f2b(v.w);
      const int c = tn4 ^ (k & 15);
      *(ushort4*)&tile[k * 64 + c * 4] = o;
    }
  }
  __syncthreads();
  {
    const int kc = t & 7;            // k-chunk of 8
    const int tn = t >> 3;           // n (+32p)
#pragma unroll
    for (int p = 0; p < 2; ++p) {
      const int n = tn + p * 32;
      union { int4 v; ushort u[8]; } o;
#pragma unroll
      for (int j = 0; j < 8; ++j) {
        const int k = kc * 8 + j;
        const int c = (n >> 2) ^ (k & 15);
        o.u[j] = tile[k * 64 + c * 4 + (n & 3)];
      }
      *(int4*)&Wt[(size_t)(nb + n) * K + kb + kc * 8] = o.v;
    }
  }
}

// ---------- one-time V transpose: qkv V-half [2048][4096] -> vT[4096][2048] (bf16) ----------
__global__ __launch_bounds__(256) void transpose_v_bf16(
    const ushort* __restrict__ qkv, ushort* __restrict__ vT) {
  __shared__ ushort tile[64 * 64];
  const int s0 = blockIdx.y * 64, c0 = blockIdx.x * 64;
  const int t = threadIdx.x;
  {
    const int tc8 = t & 7, ts = t >> 3;     // ts in [0,32)
#pragma unroll
    for (int p = 0; p < 2; ++p) {
      const int s = ts + p * 32;
      int4 x = *(const int4*)(qkv + (size_t)(s0 + s) * 12288 + 8192 + c0 + tc8 * 8);
      const int c8 = tc8 ^ (s & 7) ^ ((s >> 3) & 7);
      *(int4*)&tile[s * 64 + c8 * 8] = x;
    }
  }
  __syncthreads();
  {
    const int sc = t & 7, tc = t >> 3;      // tc in [0,32)
#pragma unroll
    for (int p = 0; p < 2; ++p) {
      const int c = tc + p * 32;
      union { int4 v; ushort u[8]; } o;
#pragma unroll
      for (int j = 0; j < 8; ++j) {
        const int s = sc * 8 + j;
        const int c8 = (c >> 3) ^ (s & 7) ^ ((s >> 3) & 7);
        o.u[j] = tile[s * 64 + c8 * 8 + (c & 7)];
      }
      *(int4*)&vT[(size_t)(c0 + c) * 2048 + s0 + sc * 8] = o.v;
    }
  }
}

// ---------- C[M][N] = A[M][K] @ Bt[N][K]^T + bias(fp32); bf16 in; out bf16 or fp32 ----------
// T3-minimum schedule: double-buffered LDS, STAGE(t+1) issued BEFORE compute(t),
// ONE barrier per K-tile (implicit vmcnt(0) drain lands after the MFMA cluster).
// T2 chunk-XOR swizzle: pre-swizzled global source + linear gl_lds dest + XOR'd read.
template <bool F32OUT>
__global__ __launch_bounds__(256) void gemm_bt_bias(
    const ushort* __restrict__ A, const ushort* __restrict__ Bt,
    const float* __restrict__ bias, void* __restrict__ Cout,
    int ldc, int M, int N, int K) {
  __shared__ ushort sA[2][128 * 64];
  __shared__ ushort sB[2][128 * 64];   // 64 KB -> 2 blocks/CU
  const int tid = threadIdx.x;
  const int lane = tid & 63, w = tid >> 6;
  const int lm = lane & 15, lq = lane >> 4;
  const int wr = w >> 1, wc = w & 1;
  const int m0 = blockIdx.y * 128, n0 = blockIdx.x * 128;
  floatx4 acc[4][4] = {};

  // staging: wave w covers tile rows [w*32, w*32+32); one instr = 8 rows x 64 cols.
  // source col chunk pre-swizzled by row&7 (= lane>>3 since base rows are %8==0).
  const int srow = w * 32 + (lane >> 3);     // + j*8
  const int scolsw = ((lane & 7) ^ (lane >> 3)) * 8;
  const ushort* Ag = A + (size_t)(m0 + srow) * K + scolsw;
  const ushort* Bg = Bt + (size_t)(n0 + srow) * K + scolsw;

  // prologue: stage tile 0 into buf 0, drain
#pragma unroll
  for (int j = 0; j < 4; ++j) {
    gl_lds16(Ag + (size_t)j * 8 * K, &sA[0][(w * 32 + j * 8) * 64]);
    gl_lds16(Bg + (size_t)j * 8 * K, &sB[0][(w * 32 + j * 8) * 64]);
  }
  __syncthreads();

  int cur = 0;
  for (int k0 = 0; k0 < K; k0 += 64) {
    // prefetch tile t+1 into the other buffer (its readers finished at end of t-1)
    if (k0 + 64 < K) {
#pragma unroll
      for (int j = 0; j < 4; ++j) {
        gl_lds16(Ag + (size_t)j * 8 * K + k0 + 64, &sA[cur ^ 1][(w * 32 + j * 8) * 64]);
        gl_lds16(Bg + (size_t)j * 8 * K + k0 + 64, &sB[cur ^ 1][(w * 32 + j * 8) * 64]);
      }
    }
    // compute tile t from buf cur (conflict-free swizzled reads: 2-way max)
#pragma unroll
    for (int ks = 0; ks < 2; ++ks) {
      short8 af[4], bf[4];
#pragma unroll
      for (int i = 0; i < 4; ++i)
        af[i] = *(const short8*)&sA[cur][(wr * 64 + i * 16 + lm) * 64 +
                                         (((ks * 4 + lq) ^ (lm & 7)) * 8)];
#pragma unroll
      for (int j = 0; j < 4; ++j)
        bf[j] = *(const short8*)&sB[cur][(wc * 64 + j * 16 + lm) * 64 +
                                         (((ks * 4 + lq) ^ (lm & 7)) * 8)];
#pragma unroll
      for (int i = 0; i < 4; ++i)
#pragma unroll
        for (int j = 0; j < 4; ++j)
          acc[i][j] = __builtin_amdgcn_mfma_f32_16x16x32_bf16(af[i], bf[j], acc[i][j], 0, 0, 0);
    }
    __syncthreads();  // drains vmcnt(0): tile t+1 landed; all reads of buf cur done
    cur ^= 1;
  }
#pragma unroll
  for (int i = 0; i < 4; ++i) {
#pragma unroll
    for (int j = 0; j < 4; ++j) {
      const int row = m0 + wr * 64 + i * 16 + lq * 4;
      const int col = n0 + wc * 64 + j * 16 + lm;
      const float bs = bias[col];
      if (F32OUT) {
        float* C = (float*)Cout;
#pragma unroll
        for (int r = 0; r < 4; ++r)
          C[(size_t)(row + r) * ldc + col] = acc[i][j][r] + bs;
      } else {
        ushort* C = (ushort*)Cout;
#pragma unroll
        for (int r = 0; r < 4; ++r)
          C[(size_t)(row + r) * ldc + col] = f2b(acc[i][j][r] + bs);
      }
    }
  }
}

// ---------- RoPE in-place on q,k halves of qkv bf16 [2048][12288], int4 vectorized ----------
__global__ __launch_bounds__(256) void rope_kernel(ushort* __restrict__ qkv) {
  const int s = blockIdx.x;
  const float pos = (float)s;
  const int t = threadIdx.x;
  const int h = t >> 3, d8 = (t & 7) * 8;
  const size_t base = (size_t)s * 12288 + h * 128 + d8;
  union U { int4 v; ushort u[8]; };
  U q1, q2, k1, k2;
  q1.v = *(const int4*)(qkv + base);
  q2.v = *(const int4*)(qkv + base + 64);
  k1.v = *(const int4*)(qkv + base + 4096);
  k2.v = *(const int4*)(qkv + base + 4160);
  float sn[8], cs[8];
#pragma unroll
  for (int j = 0; j < 8; ++j) {
    const float inv_freq = exp2f(-(float)(d8 + j) * 0.20762050593045952f); // 10000^(-d/64)
    sincosf(pos * inv_freq, &sn[j], &cs[j]);
  }
  U o1, o2;
#pragma unroll
  for (int j = 0; j < 8; ++j) {
    const float x1 = b2f(q1.u[j]), x2 = b2f(q2.u[j]);
    o1.u[j] = f2b(x1 * cs[j] - x2 * sn[j]);
    o2.u[j] = f2b(x2 * cs[j] + x1 * sn[j]);
  }
  *(int4*)(qkv + base)      = o1.v;
  *(int4*)(qkv + base + 64) = o2.v;
#pragma unroll
  for (int j = 0; j < 8; ++j) {
    const float x1 = b2f(k1.u[j]), x2 = b2f(k2.u[j]);
    o1.u[j] = f2b(x1 * cs[j] - x2 * sn[j]);
    o2.u[j] = f2b(x2 * cs[j] + x1 * sn[j]);
  }
  *(int4*)(qkv + base + 4096) = o1.v;
  *(int4*)(qkv + base + 4160) = o2.v;
}

// ---------- causal flash attention: paired q-tiles (balanced 33 kv-iters/block) ----------
// 2-phase pipeline: double-buffered K/V tiles, STAGE(t+1) issued before compute(t),
// one barrier per iter (T3-minimum). sP is wave-private (no barrier needed).
// Exact defer-rescale: skip alpha pass when no row's tile-max exceeds running max.
__global__ __launch_bounds__(256) void flash_kernel(
    const ushort* __restrict__ qkv, const ushort* __restrict__ vT,
    ushort* __restrict__ attn) {
  constexpr int QKV = 12288;
  __shared__ ushort smem[36864];          // 72 KB -> 2 blocks/CU (grid-matched)
  // buf c: sK = smem + c*8192 (64x128), sV = smem + 16384 + c*8192 (128x64)
  ushort* sP = smem + 32768;              // 64 (q) x 64 (kv), wave-private rows

  const int h   = blockIdx.y;
  const int tid = threadIdx.x;
  const int lane = tid & 63, w = tid >> 6;
  const int lm = lane & 15, lq = lane >> 4;
  const int c16 = lane & 15, l4 = lane >> 4;   // K/Q staging: 16 chunks/row, 4 rows/call
  const int c8  = lane & 7,  l3 = lane >> 3;   // V staging: 8 chunks/row, 8 rows/call
  const float sc = 0.08838834764831845f * 1.4426950408889634f; // 1/sqrt(128) * log2(e)

  for (int qsel = 0; qsel < 2; ++qsel) {
    // pair long tile (31-bx) with short tile (bx): every block does 33 kv-iters
    const int qt = qsel ? (int)blockIdx.x : 31 - (int)blockIdx.x;
    const int q0 = qt * 64;
    const int nkv = qt + 1;

    __syncthreads();   // prior half fully done with LDS
    // stage Q into buf1-K region; stage tile 0 into buf0
#pragma unroll
    for (int j = 0; j < 4; ++j) {
      const int row = w * 16 + j * 4 + l4;
      const int sw = c16 ^ (row & 7);
      gl_lds16(qkv + (size_t)(q0 + row) * QKV + h * 128 + sw * 8,
               &smem[8192 + (w * 16 + j * 4) * 128]);
    }
#pragma unroll
    for (int j = 0; j < 4; ++j) {
      const int row = w * 16 + j * 4 + l4;
      const int sw = c16 ^ (row & 7);
      gl_lds16(qkv + (size_t)row * QKV + 4096 + h * 128 + sw * 8,
               &smem[(w * 16 + j * 4) * 128]);
    }
#pragma unroll
    for (int j = 0; j < 4; ++j) {
      const int vrow = w * 32 + j * 8 + l3;
      const int sw = c8 ^ (vrow & 7);
      gl_lds16(vT + (size_t)(h * 128 + vrow) * 2048 + sw * 8,
               &smem[16384 + (w * 32 + j * 8) * 64]);
    }
    __syncthreads();   // DMA drained (Q + tile 0)
    short8 aq[4];
#pragma unroll
    for (int kk = 0; kk < 4; ++kk)
      aq[kk] = *(const short8*)&smem[8192 + (w * 16 + lm) * 128 + (((kk * 4 + lq) ^ (lm & 7)) * 8)];
    __syncthreads();   // all aq reads done before iter 0 stages buf1

    floatx4 acco[8] = {};
    float mrun[4], lrun[4];
#pragma unroll
    for (int r = 0; r < 4; ++r) { mrun[r] = -1e30f; lrun[r] = 0.f; }

    for (int it = 0; it < nkv; ++it) {
      const int cur = it & 1;
      ushort* dK = smem + cur * 8192;
      ushort* dV = smem + 16384 + cur * 8192;

      // prefetch tile it+1 into the other buffer (its readers finished at end of it-1)
      if (it + 1 < nkv) {
        const int kv1 = (it + 1) * 64;
        ushort* pK = smem + (cur ^ 1) * 8192;
        ushort* pV = smem + 16384 + (cur ^ 1) * 8192;
#pragma unroll
        for (int j = 0; j < 4; ++j) {
          const int row = w * 16 + j * 4 + l4;
          const int sw = c16 ^ (row & 7);
          gl_lds16(qkv + (size_t)(kv1 + row) * QKV + 4096 + h * 128 + sw * 8,
                   &pK[(w * 16 + j * 4) * 128]);
        }
#pragma unroll
        for (int j = 0; j < 4; ++j) {
          const int vrow = w * 32 + j * 8 + l3;
          const int sw = c8 ^ (vrow & 7);
          gl_lds16(vT + (size_t)(h * 128 + vrow) * 2048 + kv1 + sw * 8,
                   &pV[(w * 32 + j * 8) * 64]);
        }
      }

      const int kv0 = it * 64;
      // S = Q K^T  (this wave: q rows w*16..w*16+15)
      floatx4 accs[4] = {};
#pragma unroll
      for (int kk = 0; kk < 4; ++kk) {
        short8 bk[4];
#pragma unroll
        for (int nt = 0; nt < 4; ++nt)
          bk[nt] = *(const short8*)&dK[(nt * 16 + lm) * 128 + (((kk * 4 + lq) ^ (lm & 7)) * 8)];
#pragma unroll
        for (int nt = 0; nt < 4; ++nt)
          accs[nt] = __builtin_amdgcn_mfma_f32_16x16x32_bf16(aq[kk], bk[nt], accs[nt], 0, 0, 0);
      }

      // scale + causal mask + tile row-max
      const bool domask = (it == nkv - 1);
      float tmax[4];
#pragma unroll
      for (int r = 0; r < 4; ++r) tmax[r] = -1e30f;
#pragma unroll
      for (int nt = 0; nt < 4; ++nt)
#pragma unroll
        for (int r = 0; r < 4; ++r) {
          float v = accs[nt][r] * sc;
          if (domask) {
            const int qrow = q0 + w * 16 + lq * 4 + r;
            const int kcol = kv0 + nt * 16 + lm;
            if (kcol > qrow) v = -1e30f;
          }
          accs[nt][r] = v;
          tmax[r] = fmaxf(tmax[r], v);
        }
      // row-max reduce (16-lane groups)
      float tr[4];
#pragma unroll
      for (int r = 0; r < 4; ++r) {
        float t = tmax[r];
#pragma unroll
        for (int off = 1; off < 16; off <<= 1) t = fmaxf(t, __shfl_xor(t, off, 64));
        tr[r] = t;
      }
      // exact defer-rescale: if no row grew its max, alpha == 1 for every row -> skip
      unsigned long long need = 0;
#pragma unroll
      for (int r = 0; r < 4; ++r) need |= __ballot(tr[r] > mrun[r]);
      if (need) {
#pragma unroll
        for (int r = 0; r < 4; ++r) {
          const float mnew = fmaxf(mrun[r], tr[r]);
          const float alpha = exp2f(mrun[r] - mnew);
          mrun[r] = mnew;
          lrun[r] *= alpha;
#pragma unroll
          for (int nt = 0; nt < 8; ++nt) acco[nt][r] *= alpha;
        }
      }
      // P = exp2(s - m) -> sP (wave-private rows, chunk-swizzled)
      float rsum[4] = {};
#pragma unroll
      for (int nt = 0; nt < 4; ++nt)
#pragma unroll
        for (int r = 0; r < 4; ++r) {
          const float p = exp2f(accs[nt][r] - mrun[r]);
          rsum[r] += p;
          sP[(w * 16 + lq * 4 + r) * 64 +
             (((2 * nt + (lm >> 3)) ^ ((lq * 4 + r) & 7)) * 8) + (lm & 7)] = f2b(p);
        }
#pragma unroll
      for (int r = 0; r < 4; ++r) {
        float t = rsum[r];
#pragma unroll
        for (int off = 1; off < 16; off <<= 1) t += __shfl_xor(t, off, 64);
        lrun[r] += t;
      }

      // O += P @ V
#pragma unroll
      for (int ks = 0; ks < 2; ++ks) {
        const short8 ap = *(const short8*)&sP[(w * 16 + lm) * 64 + (((ks * 4 + lq) ^ (lm & 7)) * 8)];
#pragma unroll
        for (int nt = 0; nt < 8; ++nt) {
          const short8 bv = *(const short8*)&dV[(nt * 16 + lm) * 64 + (((ks * 4 + lq) ^ (lm & 7)) * 8)];
          acco[nt] = __builtin_amdgcn_mfma_f32_16x16x32_bf16(ap, bv, acco[nt], 0, 0, 0);
        }
      }
      __syncthreads();  // next tile's DMA drained (vmcnt0+lgkm0 implied); readers of cur done
    }

    // epilogue: O / l -> attn
#pragma unroll
    for (int r = 0; r < 4; ++r) {
      const float inv = 1.0f / lrun[r];
      const int row = q0 + w * 16 + lq * 4 + r;
#pragma unroll
      for (int nt = 0; nt < 8; ++nt) {
        const int col = h * 128 + nt * 16 + lm;
        attn[(size_t)row * 4096 + col] = f2b(acco[nt][r] * inv);
      }
    }
  }
}

extern "C" void kernel_launch(void* const* d_in, const int* in_sizes, int n_in,
                              void* d_out, int out_size, void* d_ws, size_t ws_size,
                              hipStream_t stream) {
  // inputs (fp32): 0=positions(int, unused), 1=hidden [2048][4096],
  // 2=Wqkv [4096][12288], 3=bqkv [12288], 4=Wo [4096][4096], 5=bo [4096].
  // Output fp32 [2048][4096].
  const float* hidden = (const float*)d_in[1];
  const float* Wqkv   = (const float*)d_in[2];
  const float* bqkv   = (const float*)d_in[3];
  const float* Wo     = (const float*)d_in[4];
  const float* bo     = (const float*)d_in[5];

  // ws layout (bf16 elements):
  //   hb   @ 0          8,388,608  (16 MiB)
  //   qkv  @ 8,388,608 25,165,824  (48 MiB)
  //   attn @33,554,432  8,388,608  (16 MiB)
  //   Wt   @41,943,040  fused: 50,331,648 el (96 MiB, full Wqkv^T) -> peak 176 MiB
  //                     fallback: 16,777,216 el (32 MiB)          -> peak 112 MiB
  ushort* ws   = (ushort*)d_ws;
  ushort* hb   = ws;
  ushort* qkv  = ws + (size_t)8388608;
  ushort* attn = ws + (size_t)33554432;
  ushort* Wt   = ws + (size_t)41943040;

  cvt_f32_bf16<<<8192, 256, 0, stream>>>(hidden, hb, 2097152);

  const bool fused = ws_size >= (size_t)184549376;  // 176 MiB
  if (fused) {
    // one transpose + one M=2048,N=12288,K=4096 GEMM (1536 blocks)
    transpose_f32_bf16<<<dim3(192, 64), 256, 0, stream>>>(Wqkv, 12288, Wt, 4096);
    gemm_bt_bias<false><<<dim3(96, 16), 256, 0, stream>>>(
        hb, Wt, bqkv, (void*)qkv, 12288, 2048, 12288, 4096);
  } else {
    for (int c = 0; c < 3; ++c) {
      transpose_f32_bf16<<<dim3(64, 64), 256, 0, stream>>>(Wqkv + c * 4096, 12288, Wt, 4096);
      gemm_bt_bias<false><<<dim3(32, 16), 256, 0, stream>>>(
          hb, Wt, bqkv + c * 4096, (void*)(qkv + c * 4096), 12288, 2048, 4096, 4096);
    }
  }

  rope_kernel<<<2048, 256, 0, stream>>>(qkv);
  // vT[4096][2048] into the (now idle) Wt region
  transpose_v_bf16<<<dim3(64, 32), 256, 0, stream>>>(qkv, Wt);
  flash_kernel<<<dim3(16, 32), 256, 0, stream>>>(qkv, Wt, attn);

  transpose_f32_bf16<<<dim3(64, 64), 256, 0, stream>>>(Wo, 4096, Wt, 4096);
  gemm_bt_bias<true><<<dim3(32, 16), 256, 0, stream>>>(
      attn, Wt, bo, d_out, 4096, 2048, 4096, 4096);
}